// Round 9
// baseline (170.967 us; speedup 1.0000x reference)
//
#include <hip/hip_runtime.h>
#include <math.h>

#define NB 16
#define NPAIR 8
#define NBINS 725
#define NPIX (1024*1024)

// Skewed LDS slot map: slot(idx,c) = idx*9 + c + (idx>>5). Stride-9 (odd)
// keeps every access pattern at the b64 2-lanes-per-bank-pair floor.
#define SLOT(idx, c) ((idx)*9 + (c) + ((idx)>>5))
#define SH_SIZE 9248

__device__ __forceinline__ constexpr int rev5(int j) {
    return ((j&1)<<4) | ((j&2)<<2) | (j&4) | ((j&8)>>2) | ((j&16)>>4);
}

// Fully-unrolled in-register 32-point FFT (input bit-reversed, output natural).
__device__ __forceinline__ void fft32(float2* r) {
    const float wr[16] = {1.f, 0.98078528f, 0.92387953f, 0.83146961f,
                          0.70710678f, 0.55557023f, 0.38268343f, 0.19509032f,
                          0.f, -0.19509032f, -0.38268343f, -0.55557023f,
                          -0.70710678f, -0.83146961f, -0.92387953f, -0.98078528f};
    const float wi[16] = {0.f, -0.19509032f, -0.38268343f, -0.55557023f,
                          -0.70710678f, -0.83146961f, -0.92387953f, -0.98078528f,
                          -1.f, -0.98078528f, -0.92387953f, -0.83146961f,
                          -0.70710678f, -0.55557023f, -0.38268343f, -0.19509032f};
    #pragma unroll
    for (int s = 1; s <= 5; ++s) {
        const int half = 1 << (s - 1);
        #pragma unroll
        for (int g = 0; g < 32; g += (1 << s)) {
            #pragma unroll
            for (int j = 0; j < half; ++j) {
                const float cw = wr[j << (5 - s)], sw = wi[j << (5 - s)];
                int i1 = g + j, i2 = i1 + half;
                float2 u = r[i1], v = r[i2];
                float2 vw = make_float2(v.x * cw - v.y * sw, v.x * sw + v.y * cw);
                r[i1] = make_float2(u.x + vw.x, u.y + vw.y);
                r[i2] = make_float2(u.x - vw.x, u.y - vw.y);
            }
        }
    }
}

// Twiddle by W_1024^(n1*k2), k2 = 0..31, via one sincos + recurrence.
__device__ __forceinline__ void twiddle1024(float2* r, int n1) {
    float sn, cs;
    sincosf((float)n1 * -0.006135923151542565f, &sn, &cs);
    float wx = 1.f, wy = 0.f;
    #pragma unroll
    for (int k2 = 0; k2 < 32; ++k2) {
        float2 s = r[k2];
        r[k2] = make_float2(s.x * wx - s.y * wy, s.x * wy + s.y * wx);
        float nx = wx * cs - wy * sn;
        wy = wx * sn + wy * cs;
        wx = nx;
    }
}

__device__ __forceinline__ int radial_bin(int ky, int kx) {
    int dy = ky - 512, dx = kx - 512;
    int d2 = dy * dy + dx * dx;
    int bin = (int)sqrtf((float)d2);
    if ((bin + 1) * (bin + 1) <= d2) ++bin;
    else if (bin * bin > d2) --bin;
    return bin;
}

// Mirror-paired column groups (bijection over 0..1023 across k=0..127).
__device__ __forceinline__ int col_of(int k, int c) {
    if (k == 0) return (c < 4) ? c : ((c == 4) ? 512 : 1028 - c);
    int a = k << 2;
    return (c < 4) ? (a + c) : (1017 + c - a);
}
__device__ __forceinline__ int mir_of(int k, int c) {
    if (k == 0) return (c == 0 || c == 4) ? c : ((c < 4) ? c + 4 : c - 4);
    return 7 - c;
}

// Pass 1: row FFTs (four-step 32x32), output written TRANSPOSED:
// spec_T[p][x][y]. Transpose staged through the skewed LDS tile.
__global__ __launch_bounds__(256, 2) void fft_rows(const float* __restrict__ in,
                                                   float2* __restrict__ spec) {
    __shared__ float2 sh[SH_SIZE];
    int tid = threadIdx.x, blk = blockIdx.x;
    int p = blk >> 7, y0 = (blk & 127) << 3;
    int n1 = tid & 31, c = tid >> 5;
    const float* xr = in + (((size_t)(2 * p)) << 20) + ((size_t)(y0 + c) << 10);
    const float* yr = xr + (1u << 20);
    float2 r[32];
    #pragma unroll
    for (int j = 0; j < 32; ++j) {
        int n = n1 + (rev5(j) << 5);
        r[j] = make_float2(xr[n], yr[n]);
    }
    fft32(r);
    twiddle1024(r, n1);
    int sb = 9 * n1 + c;
    #pragma unroll
    for (int k2 = 0; k2 < 32; ++k2) sh[sb + 289 * k2] = r[k2];
    __syncthreads();
    int k2 = tid & 31;
    int rb = 289 * k2 + c;
    #pragma unroll
    for (int j = 0; j < 32; ++j) r[j] = sh[rb + 9 * rev5(j)];
    fft32(r);
    __syncthreads();
    int wb = 9 * k2 + c;
    #pragma unroll
    for (int k1 = 0; k1 < 32; ++k1) sh[wb + 289 * k1] = r[k1];
    __syncthreads();
    float2* base = spec + (((size_t)p) << 20);
    for (int rep = 0; rep < 32; ++rep) {
        int idx = (rep << 8) + tid;
        int kcol = idx >> 3, cc = idx & 7;
        base[((size_t)kcol << 10) + y0 + cc] = sh[SLOT(kcol, cc)];
    }
}

// Pass 2: column FFTs. Round-1 reads DIRECT from global (spec_T contiguous).
// One LDS exchange; mirror rows staged in LDS; per-batch powers written IN
// PLACE over spec rows ky<=512 (zeros in skipped cells).
__global__ __launch_bounds__(256, 2) void fft_cols_pow(float2* __restrict__ spec) {
    __shared__ float2 sh[SH_SIZE];
    int tid = threadIdx.x, blk = blockIdx.x;
    int p = blk >> 7, k = blk & 127;
    int n1 = tid & 31, c = tid >> 5;
    int x = col_of(k, c), mc = mir_of(k, c);
    float2* base = spec + (((size_t)p) << 20);
    float2* colp = base + ((size_t)x << 10);
    float2 r[32];
    #pragma unroll
    for (int j = 0; j < 32; ++j) r[j] = colp[n1 + (rev5(j) << 5)];
    fft32(r);
    twiddle1024(r, n1);
    int sb = 9 * n1 + c;
    #pragma unroll
    for (int q = 0; q < 32; ++q) sh[sb + 289 * q] = r[q];
    __syncthreads();
    int k2 = tid & 31;
    int rb = 289 * k2 + c;
    #pragma unroll
    for (int j = 0; j < 32; ++j) r[j] = sh[rb + 9 * rev5(j)];
    __syncthreads();                      // exchange reads done; buffer reused
    fft32(r);
    // stage mirror rows: row 0 -> slot 0; rows 512..1023 -> slot row-511
    if (k2 == 0) sh[SLOT(0, c)] = r[0];
    #pragma unroll
    for (int k1 = 16; k1 < 32; ++k1)
        sh[SLOT(k2 + (k1 << 5) - 511, c)] = r[k1];
    __syncthreads();
    // epilogue: this thread owns ky = k2 + 32*k1 (<= 512)
    const float inv = 1.0f / (float)NPIX;
    bool xhi = (x > 512);
    #pragma unroll
    for (int k1 = 0; k1 < 17; ++k1) {
        int ky = k2 + (k1 << 5);
        if (ky > 512) break;              // only k2==0 reaches k1==16
        bool ek = ((ky & 511) == 0);
        float2 outv = make_float2(0.f, 0.f);
        if (!(ek && xhi) && !(ky == 0 && x == 0)) {
            int my = (1024 - ky) & 1023;
            int mi = (my == 0) ? 0 : my - 511;
            float2 f1 = r[k1];
            float2 f2 = sh[SLOT(mi, mc)];
            float xrr = 0.5f * (f1.x + f2.x), xii = 0.5f * (f1.y - f2.y);
            float yrr = 0.5f * (f1.y + f2.y), yii = 0.5f * (f2.x - f1.x);
            outv = make_float2((xrr * xrr + xii * xii) * inv,
                               (yrr * yrr + yii * yii) * inv);
        }
        colp[ky] = outv;                  // in-place: rows this block read
    }
}

// Pass 3: hist over packed powers. Grid split by ky-segment for occupancy:
// 2048 blocks = (pair, ch, seg). Loads pre-gathered into registers; 4x-rep
// LDS hists; merge into partial[b][bin][ch] via 2-way global atomics.
__global__ __launch_bounds__(256) void radial_hist(const float2* __restrict__ spec,
                                                   float* __restrict__ partial,
                                                   float* __restrict__ sumP2) {
    __shared__ float hs[4][2][NBINS];
    __shared__ float wred[8];
    int tid = threadIdx.x, blk = blockIdx.x;
    int p = blk >> 8, ch = (blk >> 1) & 127, seg = blk & 1;
    int ky0 = seg ? 257 : 0, ky1 = seg ? 513 : 257;
    for (int i = tid; i < 4 * 2 * NBINS; i += 256) ((float*)hs)[i] = 0.f;
    __syncthreads();
    const float2* base = spec + ((size_t)p << 20) + (((size_t)ch << 3) << 10);
    int rep = tid & 3;
    float s2e = 0.f, s2o = 0.f;
    for (int it = 0; it < 2; ++it) {
        int ky = ky0 + (it << 8) + tid;
        if (ky >= ky1) break;
        float2 pv[8];
        #pragma unroll
        for (int cl = 0; cl < 8; ++cl) pv[cl] = base[((size_t)cl << 10) + ky];
        int dy = ky - 512, dy2 = dy * dy;
        bool ek = ((ky & 511) == 0);
        #pragma unroll
        for (int cl = 0; cl < 8; ++cl) {
            int xcol = (ch << 3) + cl;
            int dx = xcol - 512;
            int d2 = dy2 + dx * dx;
            int bin = (int)sqrtf((float)d2);
            if ((bin + 1) * (bin + 1) <= d2) ++bin;
            else if (bin * bin > d2) --bin;
            float w = ek ? (((xcol & 511) == 0) ? 1.f : 2.f) : 2.f;
            atomicAdd(&hs[rep][0][bin], w * pv[cl].x);
            atomicAdd(&hs[rep][1][bin], w * pv[cl].y);
            s2e += w * pv[cl].x * pv[cl].x;
            s2o += w * pv[cl].y * pv[cl].y;
        }
    }
    #pragma unroll
    for (int off = 32; off > 0; off >>= 1) {
        s2e += __shfl_down(s2e, off);
        s2o += __shfl_down(s2o, off);
    }
    if ((tid & 63) == 0) { wred[tid >> 6] = s2e; wred[4 + (tid >> 6)] = s2o; }
    __syncthreads();
    if (tid == 0) atomicAdd(&sumP2[2 * p], wred[0] + wred[1] + wred[2] + wred[3]);
    if (tid == 1) atomicAdd(&sumP2[2 * p + 1], wred[4] + wred[5] + wred[6] + wred[7]);
    size_t b0 = (size_t)(2 * p) * NBINS, b1 = (size_t)(2 * p + 1) * NBINS;
    for (int i = tid; i < NBINS; i += 256) {
        float v0 = hs[0][0][i] + hs[1][0][i] + hs[2][0][i] + hs[3][0][i];
        float v1 = hs[0][1][i] + hs[1][1][i] + hs[2][1][i] + hs[3][1][i];
        if (v0 != 0.f) atomicAdd(&partial[(b0 + i) * 128 + ch], v0);
        if (v1 != 0.f) atomicAdd(&partial[(b1 + i) * 128 + ch], v1);
    }
}

// Geometry-only weighted bin counts over the half-plane (DC skipped).
__global__ __launch_bounds__(256) void radial_counts(float* __restrict__ counts) {
    __shared__ float hc[NBINS];
    int tid = threadIdx.x;
    int ky = blockIdx.x;                  // 0..512
    for (int i = tid; i < NBINS; i += 256) hc[i] = 0.f;
    __syncthreads();
    bool ek = (ky & 511) == 0;
    for (int xcol = tid; xcol < 1024; xcol += 256) {
        if (ek && xcol > 512) continue;
        if (ky == 0 && xcol == 0) continue;
        float w = (ek && (xcol & 511) == 0) ? 1.f : 2.f;
        atomicAdd(&hc[radial_bin(ky, xcol)], w);
    }
    __syncthreads();
    for (int i = tid; i < NBINS; i += 256)
        if (hc[i] != 0.f) atomicAdd(&counts[i], hc[i]);
}

// Pass 4: one 64-lane wave per (b,bin) row: reduce 128 partials, store
// S^2/cnt to rowval[row]. No atomics.
__global__ __launch_bounds__(256) void reduce_loss(const float* __restrict__ partial,
                                                   const float* __restrict__ counts,
                                                   float* __restrict__ rowval) {
    int row = (blockIdx.x << 2) + (threadIdx.x >> 6);   // b*NBINS + bin
    int lane = threadIdx.x & 63;
    const float* rp = partial + (size_t)row * 128;
    float s = rp[lane] + rp[lane + 64];
    #pragma unroll
    for (int off = 32; off > 0; off >>= 1) s += __shfl_down(s, off);
    if (lane == 0) {
        int b = row / NBINS, bin = row - b * NBINS;
        (void)b;
        float cv = counts[bin];
        rowval[row] = (cv > 0.f) ? s * s / cv : 0.f;
    }
}

// Final: out = WA/B * (sum_b sumP2[b] - sum_rows rowval[row])
__global__ __launch_bounds__(256) void final_out(const float* __restrict__ sumP2,
                                                 const float* __restrict__ rowval,
                                                 float* __restrict__ out) {
    __shared__ float red[256];
    int tid = threadIdx.x;
    float acc = 0.f;
    for (int i = tid; i < NB * NBINS; i += 256) acc -= rowval[i];
    if (tid < NB) acc += sumP2[tid];
    red[tid] = acc;
    __syncthreads();
    for (int s = 128; s > 0; s >>= 1) {
        if (tid < s) red[tid] += red[tid + s];
        __syncthreads();
    }
    if (tid == 0) out[0] = red[0] * (0.002f / 16.0f);
}

extern "C" void kernel_launch(void* const* d_in, const int* in_sizes, int n_in,
                              void* d_out, int out_size, void* d_ws, size_t ws_size,
                              hipStream_t stream) {
    const float* in = (const float*)d_in[0];
    float* out = (float*)d_out;
    char* ws = (char*)d_ws;

    float2* spec   = (float2*)ws;                                 // 64 MiB
    float* partial = (float*)(ws + ((size_t)NPAIR << 20) * sizeof(float2)); // 5.94 MB
    float* counts  = partial + (size_t)NB * NBINS * 128;
    float* sumP2   = counts + NBINS;
    float* rowval  = sumP2 + NB;

    hipMemsetAsync(partial, 0,
                   ((size_t)NB * NBINS * 128 + NBINS + NB) * sizeof(float), stream);

    fft_rows<<<NPAIR * 128, 256, 0, stream>>>(in, spec);
    fft_cols_pow<<<NPAIR * 128, 256, 0, stream>>>(spec);
    radial_counts<<<513, 256, 0, stream>>>(counts);
    radial_hist<<<NPAIR * 256, 256, 0, stream>>>(spec, partial, sumP2);
    reduce_loss<<<NB * NBINS / 4, 256, 0, stream>>>(partial, counts, rowval);
    final_out<<<1, 256, 0, stream>>>(sumP2, rowval, out);
}

// Round 10
// 167.407 us; speedup vs baseline: 1.0213x; 1.0213x over previous
//
#include <hip/hip_runtime.h>
#include <math.h>

#define NB 16
#define NPAIR 8
#define NBINS 725
#define NPIX (1024*1024)

// partial layout: inside each pair's spec region, starting at row 514
// (floats): pairBase = 514*1024*2 = 1052672. Even batch at +0, odd at
// +185600; entry (sc, bin) at sc*NBINS + bin, sc = seg*128 + ch in [0,256).
#define PAIR_PARTIAL_OFF 1052672
#define PARTIAL_BATCH_STRIDE 185600

// Skewed LDS slot map: slot(idx,c) = idx*9 + c + (idx>>5). Stride-9 (odd)
// keeps every access pattern at the b64 2-lanes-per-bank-pair floor.
#define SLOT(idx, c) ((idx)*9 + (c) + ((idx)>>5))
#define SH_SIZE 9248

__device__ __forceinline__ constexpr int rev5(int j) {
    return ((j&1)<<4) | ((j&2)<<2) | (j&4) | ((j&8)>>2) | ((j&16)>>4);
}

// Fully-unrolled in-register 32-point FFT (input bit-reversed, output natural).
__device__ __forceinline__ void fft32(float2* r) {
    const float wr[16] = {1.f, 0.98078528f, 0.92387953f, 0.83146961f,
                          0.70710678f, 0.55557023f, 0.38268343f, 0.19509032f,
                          0.f, -0.19509032f, -0.38268343f, -0.55557023f,
                          -0.70710678f, -0.83146961f, -0.92387953f, -0.98078528f};
    const float wi[16] = {0.f, -0.19509032f, -0.38268343f, -0.55557023f,
                          -0.70710678f, -0.83146961f, -0.92387953f, -0.98078528f,
                          -1.f, -0.98078528f, -0.92387953f, -0.83146961f,
                          -0.70710678f, -0.55557023f, -0.38268343f, -0.19509032f};
    #pragma unroll
    for (int s = 1; s <= 5; ++s) {
        const int half = 1 << (s - 1);
        #pragma unroll
        for (int g = 0; g < 32; g += (1 << s)) {
            #pragma unroll
            for (int j = 0; j < half; ++j) {
                const float cw = wr[j << (5 - s)], sw = wi[j << (5 - s)];
                int i1 = g + j, i2 = i1 + half;
                float2 u = r[i1], v = r[i2];
                float2 vw = make_float2(v.x * cw - v.y * sw, v.x * sw + v.y * cw);
                r[i1] = make_float2(u.x + vw.x, u.y + vw.y);
                r[i2] = make_float2(u.x - vw.x, u.y - vw.y);
            }
        }
    }
}

// Twiddle by W_1024^(n1*k2), k2 = 0..31, via one sincos + recurrence.
__device__ __forceinline__ void twiddle1024(float2* r, int n1) {
    float sn, cs;
    sincosf((float)n1 * -0.006135923151542565f, &sn, &cs);
    float wx = 1.f, wy = 0.f;
    #pragma unroll
    for (int k2 = 0; k2 < 32; ++k2) {
        float2 s = r[k2];
        r[k2] = make_float2(s.x * wx - s.y * wy, s.x * wy + s.y * wx);
        float nx = wx * cs - wy * sn;
        wy = wx * sn + wy * cs;
        wx = nx;
    }
}

__device__ __forceinline__ int radial_bin(int ky, int kx) {
    int dy = ky - 512, dx = kx - 512;
    int d2 = dy * dy + dx * dx;
    int bin = (int)sqrtf((float)d2);
    if ((bin + 1) * (bin + 1) <= d2) ++bin;
    else if (bin * bin > d2) --bin;
    return bin;
}

// Mirror-paired column groups (bijection over 0..1023 across k=0..127).
__device__ __forceinline__ int col_of(int k, int c) {
    if (k == 0) return (c < 4) ? c : ((c == 4) ? 512 : 1028 - c);
    int a = k << 2;
    return (c < 4) ? (a + c) : (1017 + c - a);
}
__device__ __forceinline__ int mir_of(int k, int c) {
    if (k == 0) return (c == 0 || c == 4) ? c : ((c < 4) ? c + 4 : c - 4);
    return 7 - c;
}

// Pass 1: row FFTs (four-step 32x32), output written TRANSPOSED:
// spec_T[p][x][y]. Transpose staged through the skewed LDS tile.
__global__ __launch_bounds__(256, 2) void fft_rows(const float* __restrict__ in,
                                                   float2* __restrict__ spec) {
    __shared__ float2 sh[SH_SIZE];
    int tid = threadIdx.x, blk = blockIdx.x;
    int p = blk >> 7, y0 = (blk & 127) << 3;
    int n1 = tid & 31, c = tid >> 5;
    const float* xr = in + (((size_t)(2 * p)) << 20) + ((size_t)(y0 + c) << 10);
    const float* yr = xr + (1u << 20);
    float2 r[32];
    #pragma unroll
    for (int j = 0; j < 32; ++j) {
        int n = n1 + (rev5(j) << 5);
        r[j] = make_float2(xr[n], yr[n]);
    }
    fft32(r);
    twiddle1024(r, n1);
    int sb = 9 * n1 + c;
    #pragma unroll
    for (int k2 = 0; k2 < 32; ++k2) sh[sb + 289 * k2] = r[k2];
    __syncthreads();
    int k2 = tid & 31;
    int rb = 289 * k2 + c;
    #pragma unroll
    for (int j = 0; j < 32; ++j) r[j] = sh[rb + 9 * rev5(j)];
    fft32(r);
    __syncthreads();
    int wb = 9 * k2 + c;
    #pragma unroll
    for (int k1 = 0; k1 < 32; ++k1) sh[wb + 289 * k1] = r[k1];
    __syncthreads();
    float2* base = spec + (((size_t)p) << 20);
    for (int rep = 0; rep < 32; ++rep) {
        int idx = (rep << 8) + tid;
        int kcol = idx >> 3, cc = idx & 7;
        base[((size_t)kcol << 10) + y0 + cc] = sh[SLOT(kcol, cc)];
    }
}

// Pass 2: column FFTs. Round-1 reads DIRECT from global (spec_T contiguous).
// One LDS exchange; mirror rows staged in LDS; per-batch powers written IN
// PLACE over spec rows ky<=512 (zeros in skipped cells).
__global__ __launch_bounds__(256, 2) void fft_cols_pow(float2* __restrict__ spec) {
    __shared__ float2 sh[SH_SIZE];
    int tid = threadIdx.x, blk = blockIdx.x;
    int p = blk >> 7, k = blk & 127;
    int n1 = tid & 31, c = tid >> 5;
    int x = col_of(k, c), mc = mir_of(k, c);
    float2* base = spec + (((size_t)p) << 20);
    float2* colp = base + ((size_t)x << 10);
    float2 r[32];
    #pragma unroll
    for (int j = 0; j < 32; ++j) r[j] = colp[n1 + (rev5(j) << 5)];
    fft32(r);
    twiddle1024(r, n1);
    int sb = 9 * n1 + c;
    #pragma unroll
    for (int q = 0; q < 32; ++q) sh[sb + 289 * q] = r[q];
    __syncthreads();
    int k2 = tid & 31;
    int rb = 289 * k2 + c;
    #pragma unroll
    for (int j = 0; j < 32; ++j) r[j] = sh[rb + 9 * rev5(j)];
    __syncthreads();                      // exchange reads done; buffer reused
    fft32(r);
    // stage mirror rows: row 0 -> slot 0; rows 512..1023 -> slot row-511
    if (k2 == 0) sh[SLOT(0, c)] = r[0];
    #pragma unroll
    for (int k1 = 16; k1 < 32; ++k1)
        sh[SLOT(k2 + (k1 << 5) - 511, c)] = r[k1];
    __syncthreads();
    // epilogue: this thread owns ky = k2 + 32*k1 (<= 512)
    const float inv = 1.0f / (float)NPIX;
    bool xhi = (x > 512);
    #pragma unroll
    for (int k1 = 0; k1 < 17; ++k1) {
        int ky = k2 + (k1 << 5);
        if (ky > 512) break;              // only k2==0 reaches k1==16
        bool ek = ((ky & 511) == 0);
        float2 outv = make_float2(0.f, 0.f);
        if (!(ek && xhi) && !(ky == 0 && x == 0)) {
            int my = (1024 - ky) & 1023;
            int mi = (my == 0) ? 0 : my - 511;
            float2 f1 = r[k1];
            float2 f2 = sh[SLOT(mi, mc)];
            float xrr = 0.5f * (f1.x + f2.x), xii = 0.5f * (f1.y - f2.y);
            float yrr = 0.5f * (f1.y + f2.y), yii = 0.5f * (f2.x - f1.x);
            outv = make_float2((xrr * xrr + xii * xii) * inv,
                               (yrr * yrr + yii * yii) * inv);
        }
        colp[ky] = outv;                  // in-place: rows this block read
    }
}

// Pass 3: hist over packed powers. 2048 blocks = (pair, ch, ky-segment);
// small 11.6KB 2x-replicated LDS hists (8 blocks/CU resident); partials
// stored COALESCED into the dead rows of the pair's spec region.
__global__ __launch_bounds__(256) void radial_hist(float2* __restrict__ spec,
                                                   float* __restrict__ sumP2) {
    __shared__ float hs[2][2][NBINS];
    __shared__ float wred[8];
    int tid = threadIdx.x, blk = blockIdx.x;
    int p = blk >> 8, ch = (blk >> 1) & 127, seg = blk & 1;
    for (int i = tid; i < 2 * 2 * NBINS; i += 256) ((float*)hs)[i] = 0.f;
    __syncthreads();
    const float2* base = spec + ((size_t)p << 20) + (((size_t)ch << 3) << 10);
    int rep = tid & 1;
    float s2e = 0.f, s2o = 0.f;
    for (int ky = (seg << 8) + tid; ky <= 512; ky += 256) {
        if (!seg && ky > 255) break;      // seg0: ky 0..255; seg1: 256..512
        float2 pv[8];
        #pragma unroll
        for (int cl = 0; cl < 8; ++cl) pv[cl] = base[((size_t)cl << 10) + ky];
        int dy = ky - 512, dy2 = dy * dy;
        bool ek = ((ky & 511) == 0);
        #pragma unroll
        for (int cl = 0; cl < 8; ++cl) {
            int xcol = (ch << 3) + cl;
            int dx = xcol - 512;
            int d2 = dy2 + dx * dx;
            int bin = (int)sqrtf((float)d2);
            if ((bin + 1) * (bin + 1) <= d2) ++bin;
            else if (bin * bin > d2) --bin;
            float w = ek ? (((xcol & 511) == 0) ? 1.f : 2.f) : 2.f;
            atomicAdd(&hs[rep][0][bin], w * pv[cl].x);
            atomicAdd(&hs[rep][1][bin], w * pv[cl].y);
            s2e += w * pv[cl].x * pv[cl].x;
            s2o += w * pv[cl].y * pv[cl].y;
        }
    }
    #pragma unroll
    for (int off = 32; off > 0; off >>= 1) {
        s2e += __shfl_down(s2e, off);
        s2o += __shfl_down(s2o, off);
    }
    if ((tid & 63) == 0) { wred[tid >> 6] = s2e; wred[4 + (tid >> 6)] = s2o; }
    __syncthreads();
    if (tid == 0) atomicAdd(&sumP2[2 * p], wred[0] + wred[1] + wred[2] + wred[3]);
    if (tid == 1) atomicAdd(&sumP2[2 * p + 1], wred[4] + wred[5] + wred[6] + wred[7]);
    // coalesced partial store: slice (sc = seg*128+ch) of this pair's region
    float* pbase = (float*)(spec + ((size_t)p << 20)) + PAIR_PARTIAL_OFF;
    int sc = (seg << 7) | ch;
    float* pe = pbase + (size_t)sc * NBINS;
    float* po = pe + PARTIAL_BATCH_STRIDE;
    for (int i = tid; i < NBINS; i += 256) {
        pe[i] = hs[0][0][i] + hs[1][0][i];
        po[i] = hs[0][1][i] + hs[1][1][i];
    }
}

// Geometry-only weighted bin counts over the half-plane (DC skipped).
__global__ __launch_bounds__(256) void radial_counts(float* __restrict__ counts) {
    __shared__ float hc[NBINS];
    int tid = threadIdx.x;
    int ky = blockIdx.x;                  // 0..512
    for (int i = tid; i < NBINS; i += 256) hc[i] = 0.f;
    __syncthreads();
    bool ek = (ky & 511) == 0;
    for (int xcol = tid; xcol < 1024; xcol += 256) {
        if (ek && xcol > 512) continue;
        if (ky == 0 && xcol == 0) continue;
        float w = (ek && (xcol & 511) == 0) ? 1.f : 2.f;
        atomicAdd(&hc[radial_bin(ky, xcol)], w);
    }
    __syncthreads();
    for (int i = tid; i < NBINS; i += 256)
        if (hc[i] != 0.f) atomicAdd(&counts[i], hc[i]);
}

// Pass 4: one 64-lane wave per (b,bin) row: reduce 256 sc-slices, store
// S^2/cnt to rowval[row]. No atomics.
__global__ __launch_bounds__(256) void reduce_loss(const float2* __restrict__ spec,
                                                   const float* __restrict__ counts,
                                                   float* __restrict__ rowval) {
    int row = (blockIdx.x << 2) + (threadIdx.x >> 6);   // b*NBINS + bin
    int lane = threadIdx.x & 63;
    int b = row / NBINS, bin = row - b * NBINS;
    int p = b >> 1, eo = b & 1;
    const float* rp = (const float*)(spec + ((size_t)p << 20)) + PAIR_PARTIAL_OFF
                      + (size_t)eo * PARTIAL_BATCH_STRIDE + bin;
    float s = 0.f;
    #pragma unroll
    for (int q = 0; q < 4; ++q)
        s += rp[(size_t)(lane + (q << 6)) * NBINS];
    #pragma unroll
    for (int off = 32; off > 0; off >>= 1) s += __shfl_down(s, off);
    if (lane == 0) {
        float cv = counts[bin];
        rowval[row] = (cv > 0.f) ? s * s / cv : 0.f;
    }
}

// Final: out = WA/B * (sum_b sumP2[b] - sum_rows rowval[row])
__global__ __launch_bounds__(256) void final_out(const float* __restrict__ sumP2,
                                                 const float* __restrict__ rowval,
                                                 float* __restrict__ out) {
    __shared__ float red[256];
    int tid = threadIdx.x;
    float acc = 0.f;
    for (int i = tid; i < NB * NBINS; i += 256) acc -= rowval[i];
    if (tid < NB) acc += sumP2[tid];
    red[tid] = acc;
    __syncthreads();
    for (int s = 128; s > 0; s >>= 1) {
        if (tid < s) red[tid] += red[tid + s];
        __syncthreads();
    }
    if (tid == 0) out[0] = red[0] * (0.002f / 16.0f);
}

extern "C" void kernel_launch(void* const* d_in, const int* in_sizes, int n_in,
                              void* d_out, int out_size, void* d_ws, size_t ws_size,
                              hipStream_t stream) {
    const float* in = (const float*)d_in[0];
    float* out = (float*)d_out;
    char* ws = (char*)d_ws;

    float2* spec  = (float2*)ws;                                  // 64 MiB
    float* counts = (float*)(ws + ((size_t)NPAIR << 20) * sizeof(float2));
    float* sumP2  = counts + NBINS;
    float* rowval = sumP2 + NB;

    hipMemsetAsync(counts, 0, (size_t)(NBINS + NB) * sizeof(float), stream);

    fft_rows<<<NPAIR * 128, 256, 0, stream>>>(in, spec);
    fft_cols_pow<<<NPAIR * 128, 256, 0, stream>>>(spec);
    radial_counts<<<513, 256, 0, stream>>>(counts);
    radial_hist<<<NPAIR * 256, 256, 0, stream>>>(spec, sumP2);
    reduce_loss<<<NB * NBINS / 4, 256, 0, stream>>>(spec, counts, rowval);
    final_out<<<1, 256, 0, stream>>>(sumP2, rowval, out);
}

// Round 11
// 163.421 us; speedup vs baseline: 1.0462x; 1.0244x over previous
//
#include <hip/hip_runtime.h>
#include <math.h>

#define NB 16
#define NPAIR 8
#define NBINS 725
#define NPIX (1024*1024)

// partial layout: inside each pair's spec region, starting at row 514
// (floats): pairBase = 514*1024*2 = 1052672. Even batch at +0, odd at
// +185600; entry (sc, bin) at sc*NBINS + bin, sc = seg*128 + ch in [0,256).
#define PAIR_PARTIAL_OFF 1052672
#define PARTIAL_BATCH_STRIDE 185600

// Skewed LDS slot map: slot(idx,c) = idx*9 + c + (idx>>5). Stride-9 (odd)
// keeps every access pattern at the b64 2-lanes-per-bank-pair floor.
#define SLOT(idx, c) ((idx)*9 + (c) + ((idx)>>5))
#define SH_SIZE 9248

__device__ __forceinline__ constexpr int rev5(int j) {
    return ((j&1)<<4) | ((j&2)<<2) | (j&4) | ((j&8)>>2) | ((j&16)>>4);
}

// Fully-unrolled in-register 32-point FFT (input bit-reversed, output natural).
__device__ __forceinline__ void fft32(float2* r) {
    const float wr[16] = {1.f, 0.98078528f, 0.92387953f, 0.83146961f,
                          0.70710678f, 0.55557023f, 0.38268343f, 0.19509032f,
                          0.f, -0.19509032f, -0.38268343f, -0.55557023f,
                          -0.70710678f, -0.83146961f, -0.92387953f, -0.98078528f};
    const float wi[16] = {0.f, -0.19509032f, -0.38268343f, -0.55557023f,
                          -0.70710678f, -0.83146961f, -0.92387953f, -0.98078528f,
                          -1.f, -0.98078528f, -0.92387953f, -0.83146961f,
                          -0.70710678f, -0.55557023f, -0.38268343f, -0.19509032f};
    #pragma unroll
    for (int s = 1; s <= 5; ++s) {
        const int half = 1 << (s - 1);
        #pragma unroll
        for (int g = 0; g < 32; g += (1 << s)) {
            #pragma unroll
            for (int j = 0; j < half; ++j) {
                const float cw = wr[j << (5 - s)], sw = wi[j << (5 - s)];
                int i1 = g + j, i2 = i1 + half;
                float2 u = r[i1], v = r[i2];
                float2 vw = make_float2(v.x * cw - v.y * sw, v.x * sw + v.y * cw);
                r[i1] = make_float2(u.x + vw.x, u.y + vw.y);
                r[i2] = make_float2(u.x - vw.x, u.y - vw.y);
            }
        }
    }
}

// Twiddle by W_1024^(n1*k2), k2 = 0..31, via one sincos + recurrence.
__device__ __forceinline__ void twiddle1024(float2* r, int n1) {
    float sn, cs;
    sincosf((float)n1 * -0.006135923151542565f, &sn, &cs);
    float wx = 1.f, wy = 0.f;
    #pragma unroll
    for (int k2 = 0; k2 < 32; ++k2) {
        float2 s = r[k2];
        r[k2] = make_float2(s.x * wx - s.y * wy, s.x * wy + s.y * wx);
        float nx = wx * cs - wy * sn;
        wy = wx * sn + wy * cs;
        wx = nx;
    }
}

__device__ __forceinline__ int radial_bin(int ky, int kx) {
    int dy = ky - 512, dx = kx - 512;
    int d2 = dy * dy + dx * dx;
    int bin = (int)sqrtf((float)d2);
    if ((bin + 1) * (bin + 1) <= d2) ++bin;
    else if (bin * bin > d2) --bin;
    return bin;
}

// Mirror-paired column groups (bijection over 0..1023 across k=0..127).
__device__ __forceinline__ int col_of(int k, int c) {
    if (k == 0) return (c < 4) ? c : ((c == 4) ? 512 : 1028 - c);
    int a = k << 2;
    return (c < 4) ? (a + c) : (1017 + c - a);
}
__device__ __forceinline__ int mir_of(int k, int c) {
    if (k == 0) return (c == 0 || c == 4) ? c : ((c < 4) ? c + 4 : c - 4);
    return 7 - c;
}

// Pass 1: row FFTs (four-step 32x32), output written TRANSPOSED:
// spec_T[p][x][y]. Transpose staged through the skewed LDS tile.
__global__ __launch_bounds__(256, 2) void fft_rows(const float* __restrict__ in,
                                                   float2* __restrict__ spec) {
    __shared__ float2 sh[SH_SIZE];
    int tid = threadIdx.x, blk = blockIdx.x;
    int p = blk >> 7, y0 = (blk & 127) << 3;
    int n1 = tid & 31, c = tid >> 5;
    const float* xr = in + (((size_t)(2 * p)) << 20) + ((size_t)(y0 + c) << 10);
    const float* yr = xr + (1u << 20);
    float2 r[32];
    #pragma unroll
    for (int j = 0; j < 32; ++j) {
        int n = n1 + (rev5(j) << 5);
        r[j] = make_float2(xr[n], yr[n]);
    }
    fft32(r);
    twiddle1024(r, n1);
    int sb = 9 * n1 + c;
    #pragma unroll
    for (int k2 = 0; k2 < 32; ++k2) sh[sb + 289 * k2] = r[k2];
    __syncthreads();
    int k2 = tid & 31;
    int rb = 289 * k2 + c;
    #pragma unroll
    for (int j = 0; j < 32; ++j) r[j] = sh[rb + 9 * rev5(j)];
    fft32(r);
    __syncthreads();
    int wb = 9 * k2 + c;
    #pragma unroll
    for (int k1 = 0; k1 < 32; ++k1) sh[wb + 289 * k1] = r[k1];
    __syncthreads();
    float2* base = spec + (((size_t)p) << 20);
    for (int rep = 0; rep < 32; ++rep) {
        int idx = (rep << 8) + tid;
        int kcol = idx >> 3, cc = idx & 7;
        base[((size_t)kcol << 10) + y0 + cc] = sh[SLOT(kcol, cc)];
    }
}

// Pass 2: column FFTs. Round-1 reads DIRECT from global (spec_T contiguous).
// One LDS exchange; mirror rows staged in LDS; per-batch powers written IN
// PLACE over spec rows ky<=512 (zeros in skipped cells).
__global__ __launch_bounds__(256, 2) void fft_cols_pow(float2* __restrict__ spec) {
    __shared__ float2 sh[SH_SIZE];
    int tid = threadIdx.x, blk = blockIdx.x;
    int p = blk >> 7, k = blk & 127;
    int n1 = tid & 31, c = tid >> 5;
    int x = col_of(k, c), mc = mir_of(k, c);
    float2* base = spec + (((size_t)p) << 20);
    float2* colp = base + ((size_t)x << 10);
    float2 r[32];
    #pragma unroll
    for (int j = 0; j < 32; ++j) r[j] = colp[n1 + (rev5(j) << 5)];
    fft32(r);
    twiddle1024(r, n1);
    int sb = 9 * n1 + c;
    #pragma unroll
    for (int q = 0; q < 32; ++q) sh[sb + 289 * q] = r[q];
    __syncthreads();
    int k2 = tid & 31;
    int rb = 289 * k2 + c;
    #pragma unroll
    for (int j = 0; j < 32; ++j) r[j] = sh[rb + 9 * rev5(j)];
    __syncthreads();                      // exchange reads done; buffer reused
    fft32(r);
    // stage mirror rows: row 0 -> slot 0; rows 512..1023 -> slot row-511
    if (k2 == 0) sh[SLOT(0, c)] = r[0];
    #pragma unroll
    for (int k1 = 16; k1 < 32; ++k1)
        sh[SLOT(k2 + (k1 << 5) - 511, c)] = r[k1];
    __syncthreads();
    // epilogue: this thread owns ky = k2 + 32*k1 (<= 512)
    const float inv = 1.0f / (float)NPIX;
    bool xhi = (x > 512);
    #pragma unroll
    for (int k1 = 0; k1 < 17; ++k1) {
        int ky = k2 + (k1 << 5);
        if (ky > 512) break;              // only k2==0 reaches k1==16
        bool ek = ((ky & 511) == 0);
        float2 outv = make_float2(0.f, 0.f);
        if (!(ek && xhi) && !(ky == 0 && x == 0)) {
            int my = (1024 - ky) & 1023;
            int mi = (my == 0) ? 0 : my - 511;
            float2 f1 = r[k1];
            float2 f2 = sh[SLOT(mi, mc)];
            float xrr = 0.5f * (f1.x + f2.x), xii = 0.5f * (f1.y - f2.y);
            float yrr = 0.5f * (f1.y + f2.y), yii = 0.5f * (f2.x - f1.x);
            outv = make_float2((xrr * xrr + xii * xii) * inv,
                               (yrr * yrr + yii * yii) * inv);
        }
        colp[ky] = outv;                  // in-place: rows this block read
    }
}

// Pass 3: hist over packed powers. 2048 blocks = (pair, ch, ky-segment).
// Each thread owns a run of 8 consecutive ky in ONE column; bins are
// monotone along the run, so equal-bin pixels merge in registers and only
// bin-changes flush to LDS (kills the ky~512 same-bin serialization).
// Excluded cells hold 0 (written by fft_cols_pow) -> no exclusion tests.
__global__ __launch_bounds__(256) void radial_hist(float2* __restrict__ spec,
                                                   float* __restrict__ sumP2) {
    __shared__ float hs0[NBINS], hs1[NBINS];
    __shared__ float wred[8];
    int tid = threadIdx.x, blk = blockIdx.x;
    int p = blk >> 8, ch = (blk >> 1) & 127, seg = blk & 1;
    for (int i = tid; i < NBINS; i += 256) { hs0[i] = 0.f; hs1[i] = 0.f; }
    __syncthreads();
    const float2* base = spec + ((size_t)p << 20) + (((size_t)ch << 3) << 10);
    int cl = tid & 7, chunk = tid >> 3;           // 32 chunks x 8 ky = 256 ky
    int xcol = (ch << 3) + cl;
    int dx2 = (xcol - 512) * (xcol - 512);
    int ky0 = (seg << 8) + (chunk << 3);
    const float4* lp = (const float4*)(base + ((size_t)cl << 10) + ky0);
    float2 pv[8];
    #pragma unroll
    for (int q = 0; q < 4; ++q) {
        float4 t4 = lp[q];
        pv[2 * q]     = make_float2(t4.x, t4.y);
        pv[2 * q + 1] = make_float2(t4.z, t4.w);
    }
    float s2e = 0.f, s2o = 0.f;
    int curbin = -1;
    float a0 = 0.f, a1 = 0.f;
    #pragma unroll
    for (int j = 0; j < 8; ++j) {
        int ky = ky0 + j;
        int dy = ky - 512;
        int d2 = dy * dy + dx2;
        int bin = (int)sqrtf((float)d2);
        if ((bin + 1) * (bin + 1) <= d2) ++bin;
        else if (bin * bin > d2) --bin;
        float w = ((ky & 511) == 0) ? (((xcol & 511) == 0) ? 1.f : 2.f) : 2.f;
        float v0 = w * pv[j].x, v1 = w * pv[j].y;
        s2e += v0 * pv[j].x;
        s2o += v1 * pv[j].y;
        if (bin == curbin) { a0 += v0; a1 += v1; }
        else {
            if (curbin >= 0) { atomicAdd(&hs0[curbin], a0); atomicAdd(&hs1[curbin], a1); }
            curbin = bin; a0 = v0; a1 = v1;
        }
    }
    if (curbin >= 0) { atomicAdd(&hs0[curbin], a0); atomicAdd(&hs1[curbin], a1); }
    // ky = 512 row (seg1 only): threads 0..7, one pixel each
    if (seg && tid < 8) {
        int x2 = (ch << 3) + tid;
        float2 pvv = base[((size_t)tid << 10) + 512];
        float w = ((x2 & 511) == 0) ? 1.f : 2.f;
        float v0 = w * pvv.x, v1 = w * pvv.y;
        s2e += v0 * pvv.x;
        s2o += v1 * pvv.y;
        int dx = x2 - 512;
        int bin = (dx < 0) ? -dx : dx;    // exact: dy = 0
        atomicAdd(&hs0[bin], v0);
        atomicAdd(&hs1[bin], v1);
    }
    #pragma unroll
    for (int off = 32; off > 0; off >>= 1) {
        s2e += __shfl_down(s2e, off);
        s2o += __shfl_down(s2o, off);
    }
    if ((tid & 63) == 0) { wred[tid >> 6] = s2e; wred[4 + (tid >> 6)] = s2o; }
    __syncthreads();
    if (tid == 0) atomicAdd(&sumP2[2 * p], wred[0] + wred[1] + wred[2] + wred[3]);
    if (tid == 1) atomicAdd(&sumP2[2 * p + 1], wred[4] + wred[5] + wred[6] + wred[7]);
    // coalesced partial store: slice (sc = seg*128+ch) of this pair's region
    float* pbase = (float*)(spec + ((size_t)p << 20)) + PAIR_PARTIAL_OFF;
    int sc = (seg << 7) | ch;
    float* pe = pbase + (size_t)sc * NBINS;
    float* po = pe + PARTIAL_BATCH_STRIDE;
    for (int i = tid; i < NBINS; i += 256) {
        pe[i] = hs0[i];
        po[i] = hs1[i];
    }
}

// Geometry-only weighted bin counts over the half-plane (DC skipped).
__global__ __launch_bounds__(256) void radial_counts(float* __restrict__ counts) {
    __shared__ float hc[NBINS];
    int tid = threadIdx.x;
    int ky = blockIdx.x;                  // 0..512
    for (int i = tid; i < NBINS; i += 256) hc[i] = 0.f;
    __syncthreads();
    bool ek = (ky & 511) == 0;
    for (int xcol = tid; xcol < 1024; xcol += 256) {
        if (ek && xcol > 512) continue;
        if (ky == 0 && xcol == 0) continue;
        float w = (ek && (xcol & 511) == 0) ? 1.f : 2.f;
        atomicAdd(&hc[radial_bin(ky, xcol)], w);
    }
    __syncthreads();
    for (int i = tid; i < NBINS; i += 256)
        if (hc[i] != 0.f) atomicAdd(&counts[i], hc[i]);
}

// Pass 4: one 64-lane wave per (b,bin) row: reduce 256 sc-slices, store
// S^2/cnt to rowval[row]. No atomics.
__global__ __launch_bounds__(256) void reduce_loss(const float2* __restrict__ spec,
                                                   const float* __restrict__ counts,
                                                   float* __restrict__ rowval) {
    int row = (blockIdx.x << 2) + (threadIdx.x >> 6);   // b*NBINS + bin
    int lane = threadIdx.x & 63;
    int b = row / NBINS, bin = row - b * NBINS;
    int p = b >> 1, eo = b & 1;
    const float* rp = (const float*)(spec + ((size_t)p << 20)) + PAIR_PARTIAL_OFF
                      + (size_t)eo * PARTIAL_BATCH_STRIDE + bin;
    float s = 0.f;
    #pragma unroll
    for (int q = 0; q < 4; ++q)
        s += rp[(size_t)(lane + (q << 6)) * NBINS];
    #pragma unroll
    for (int off = 32; off > 0; off >>= 1) s += __shfl_down(s, off);
    if (lane == 0) {
        float cv = counts[bin];
        rowval[row] = (cv > 0.f) ? s * s / cv : 0.f;
    }
}

// Final: out = WA/B * (sum_b sumP2[b] - sum_rows rowval[row])
__global__ __launch_bounds__(256) void final_out(const float* __restrict__ sumP2,
                                                 const float* __restrict__ rowval,
                                                 float* __restrict__ out) {
    __shared__ float red[256];
    int tid = threadIdx.x;
    float acc = 0.f;
    for (int i = tid; i < NB * NBINS; i += 256) acc -= rowval[i];
    if (tid < NB) acc += sumP2[tid];
    red[tid] = acc;
    __syncthreads();
    for (int s = 128; s > 0; s >>= 1) {
        if (tid < s) red[tid] += red[tid + s];
        __syncthreads();
    }
    if (tid == 0) out[0] = red[0] * (0.002f / 16.0f);
}

extern "C" void kernel_launch(void* const* d_in, const int* in_sizes, int n_in,
                              void* d_out, int out_size, void* d_ws, size_t ws_size,
                              hipStream_t stream) {
    const float* in = (const float*)d_in[0];
    float* out = (float*)d_out;
    char* ws = (char*)d_ws;

    float2* spec  = (float2*)ws;                                  // 64 MiB
    float* counts = (float*)(ws + ((size_t)NPAIR << 20) * sizeof(float2));
    float* sumP2  = counts + NBINS;
    float* rowval = sumP2 + NB;

    hipMemsetAsync(counts, 0, (size_t)(NBINS + NB) * sizeof(float), stream);

    fft_rows<<<NPAIR * 128, 256, 0, stream>>>(in, spec);
    fft_cols_pow<<<NPAIR * 128, 256, 0, stream>>>(spec);
    radial_counts<<<513, 256, 0, stream>>>(counts);
    radial_hist<<<NPAIR * 256, 256, 0, stream>>>(spec, sumP2);
    reduce_loss<<<NB * NBINS / 4, 256, 0, stream>>>(spec, counts, rowval);
    final_out<<<1, 256, 0, stream>>>(sumP2, rowval, out);
}

// Round 12
// 149.510 us; speedup vs baseline: 1.1435x; 1.0930x over previous
//
#include <hip/hip_runtime.h>
#include <math.h>

#define NB 16
#define NPAIR 8
#define NBINS 725
#define NPIX (1024*1024)

// partial layout: inside each pair's spec region, starting at row 514
// (floats): pairBase = 514*1024*2 = 1052672. Even batch at +0, odd at
// +185600; entry (sc, bin) at sc*NBINS + bin, sc = seg*128 + ch in [0,256).
#define PAIR_PARTIAL_OFF 1052672
#define PARTIAL_BATCH_STRIDE 185600

// Skewed LDS slot map: slot(idx,c) = idx*9 + c + (idx>>5). Stride-9 (odd)
// keeps every access pattern at the b64 2-lanes-per-bank-pair floor.
#define SLOT(idx, c) ((idx)*9 + (c) + ((idx)>>5))
#define SH_SIZE 9248

__device__ __forceinline__ constexpr int rev5(int j) {
    return ((j&1)<<4) | ((j&2)<<2) | (j&4) | ((j&8)>>2) | ((j&16)>>4);
}

// Fully-unrolled in-register 32-point FFT (input bit-reversed, output natural).
__device__ __forceinline__ void fft32(float2* r) {
    const float wr[16] = {1.f, 0.98078528f, 0.92387953f, 0.83146961f,
                          0.70710678f, 0.55557023f, 0.38268343f, 0.19509032f,
                          0.f, -0.19509032f, -0.38268343f, -0.55557023f,
                          -0.70710678f, -0.83146961f, -0.92387953f, -0.98078528f};
    const float wi[16] = {0.f, -0.19509032f, -0.38268343f, -0.55557023f,
                          -0.70710678f, -0.83146961f, -0.92387953f, -0.98078528f,
                          -1.f, -0.98078528f, -0.92387953f, -0.83146961f,
                          -0.70710678f, -0.55557023f, -0.38268343f, -0.19509032f};
    #pragma unroll
    for (int s = 1; s <= 5; ++s) {
        const int half = 1 << (s - 1);
        #pragma unroll
        for (int g = 0; g < 32; g += (1 << s)) {
            #pragma unroll
            for (int j = 0; j < half; ++j) {
                const float cw = wr[j << (5 - s)], sw = wi[j << (5 - s)];
                int i1 = g + j, i2 = i1 + half;
                float2 u = r[i1], v = r[i2];
                float2 vw = make_float2(v.x * cw - v.y * sw, v.x * sw + v.y * cw);
                r[i1] = make_float2(u.x + vw.x, u.y + vw.y);
                r[i2] = make_float2(u.x - vw.x, u.y - vw.y);
            }
        }
    }
}

// Twiddle by W_1024^(n1*k2), k2 = 0..31, via one sincos + recurrence.
__device__ __forceinline__ void twiddle1024(float2* r, int n1) {
    float sn, cs;
    sincosf((float)n1 * -0.006135923151542565f, &sn, &cs);
    float wx = 1.f, wy = 0.f;
    #pragma unroll
    for (int k2 = 0; k2 < 32; ++k2) {
        float2 s = r[k2];
        r[k2] = make_float2(s.x * wx - s.y * wy, s.x * wy + s.y * wx);
        float nx = wx * cs - wy * sn;
        wy = wx * sn + wy * cs;
        wx = nx;
    }
}

// Mirror-paired column groups (bijection over 0..1023 across k=0..127).
__device__ __forceinline__ int col_of(int k, int c) {
    if (k == 0) return (c < 4) ? c : ((c == 4) ? 512 : 1028 - c);
    int a = k << 2;
    return (c < 4) ? (a + c) : (1017 + c - a);
}
__device__ __forceinline__ int mir_of(int k, int c) {
    if (k == 0) return (c == 0 || c == 4) ? c : ((c < 4) ? c + 4 : c - 4);
    return 7 - c;
}

// Pass 1: row FFTs (four-step 32x32), output written TRANSPOSED:
// spec_T[p][x][y]. Transpose staged through the skewed LDS tile.
__global__ __launch_bounds__(256, 2) void fft_rows(const float* __restrict__ in,
                                                   float2* __restrict__ spec) {
    __shared__ float2 sh[SH_SIZE];
    int tid = threadIdx.x, blk = blockIdx.x;
    int p = blk >> 7, y0 = (blk & 127) << 3;
    int n1 = tid & 31, c = tid >> 5;
    const float* xr = in + (((size_t)(2 * p)) << 20) + ((size_t)(y0 + c) << 10);
    const float* yr = xr + (1u << 20);
    float2 r[32];
    #pragma unroll
    for (int j = 0; j < 32; ++j) {
        int n = n1 + (rev5(j) << 5);
        r[j] = make_float2(xr[n], yr[n]);
    }
    fft32(r);
    twiddle1024(r, n1);
    int sb = 9 * n1 + c;
    #pragma unroll
    for (int k2 = 0; k2 < 32; ++k2) sh[sb + 289 * k2] = r[k2];
    __syncthreads();
    int k2 = tid & 31;
    int rb = 289 * k2 + c;
    #pragma unroll
    for (int j = 0; j < 32; ++j) r[j] = sh[rb + 9 * rev5(j)];
    fft32(r);
    __syncthreads();
    int wb = 9 * k2 + c;
    #pragma unroll
    for (int k1 = 0; k1 < 32; ++k1) sh[wb + 289 * k1] = r[k1];
    __syncthreads();
    float2* base = spec + (((size_t)p) << 20);
    for (int rep = 0; rep < 32; ++rep) {
        int idx = (rep << 8) + tid;
        int kcol = idx >> 3, cc = idx & 7;
        base[((size_t)kcol << 10) + y0 + cc] = sh[SLOT(kcol, cc)];
    }
}

// Pass 2: column FFTs. Round-1 reads DIRECT from global (spec_T contiguous).
// One LDS exchange; mirror rows staged in LDS; per-batch powers written IN
// PLACE over spec rows ky<=512 (zeros in skipped cells).
__global__ __launch_bounds__(256, 2) void fft_cols_pow(float2* __restrict__ spec) {
    __shared__ float2 sh[SH_SIZE];
    int tid = threadIdx.x, blk = blockIdx.x;
    int p = blk >> 7, k = blk & 127;
    int n1 = tid & 31, c = tid >> 5;
    int x = col_of(k, c), mc = mir_of(k, c);
    float2* base = spec + (((size_t)p) << 20);
    float2* colp = base + ((size_t)x << 10);
    float2 r[32];
    #pragma unroll
    for (int j = 0; j < 32; ++j) r[j] = colp[n1 + (rev5(j) << 5)];
    fft32(r);
    twiddle1024(r, n1);
    int sb = 9 * n1 + c;
    #pragma unroll
    for (int q = 0; q < 32; ++q) sh[sb + 289 * q] = r[q];
    __syncthreads();
    int k2 = tid & 31;
    int rb = 289 * k2 + c;
    #pragma unroll
    for (int j = 0; j < 32; ++j) r[j] = sh[rb + 9 * rev5(j)];
    __syncthreads();                      // exchange reads done; buffer reused
    fft32(r);
    // stage mirror rows: row 0 -> slot 0; rows 512..1023 -> slot row-511
    if (k2 == 0) sh[SLOT(0, c)] = r[0];
    #pragma unroll
    for (int k1 = 16; k1 < 32; ++k1)
        sh[SLOT(k2 + (k1 << 5) - 511, c)] = r[k1];
    __syncthreads();
    // epilogue: this thread owns ky = k2 + 32*k1 (<= 512)
    const float inv = 1.0f / (float)NPIX;
    bool xhi = (x > 512);
    #pragma unroll
    for (int k1 = 0; k1 < 17; ++k1) {
        int ky = k2 + (k1 << 5);
        if (ky > 512) break;              // only k2==0 reaches k1==16
        bool ek = ((ky & 511) == 0);
        float2 outv = make_float2(0.f, 0.f);
        if (!(ek && xhi) && !(ky == 0 && x == 0)) {
            int my = (1024 - ky) & 1023;
            int mi = (my == 0) ? 0 : my - 511;
            float2 f1 = r[k1];
            float2 f2 = sh[SLOT(mi, mc)];
            float xrr = 0.5f * (f1.x + f2.x), xii = 0.5f * (f1.y - f2.y);
            float yrr = 0.5f * (f1.y + f2.y), yii = 0.5f * (f2.x - f1.x);
            outv = make_float2((xrr * xrr + xii * xii) * inv,
                               (yrr * yrr + yii * yii) * inv);
        }
        colp[ky] = outv;                  // in-place: rows this block read
    }
}

// Pass 3: hist over packed powers. 2048 blocks = (pair, ch, ky-segment).
// Run-of-8-ky-per-thread with register bin-merging. p==0 blocks also build
// the geometry count hist (exclusion-aware). NO GLOBAL ATOMICS: block s2
// partials -> s2buf plain stores; hist partials -> coalesced slices.
__global__ __launch_bounds__(256) void radial_hist(float2* __restrict__ spec,
                                                   float* __restrict__ s2buf,
                                                   float* __restrict__ cntp) {
    __shared__ float hs0[NBINS], hs1[NBINS], hc[NBINS];
    __shared__ float wred[8];
    int tid = threadIdx.x, blk = blockIdx.x;
    int p = blk >> 8, ch = (blk >> 1) & 127, seg = blk & 1;
    bool docnt = (p == 0);
    for (int i = tid; i < NBINS; i += 256) { hs0[i] = 0.f; hs1[i] = 0.f; hc[i] = 0.f; }
    __syncthreads();
    const float2* base = spec + ((size_t)p << 20) + (((size_t)ch << 3) << 10);
    int cl = tid & 7, chunk = tid >> 3;           // 32 chunks x 8 ky = 256 ky
    int xcol = (ch << 3) + cl;
    int dx2 = (xcol - 512) * (xcol - 512);
    bool xs = ((xcol & 511) == 0), xhi = (xcol > 512);
    int ky0 = (seg << 8) + (chunk << 3);
    const float4* lp = (const float4*)(base + ((size_t)cl << 10) + ky0);
    float2 pv[8];
    #pragma unroll
    for (int q = 0; q < 4; ++q) {
        float4 t4 = lp[q];
        pv[2 * q]     = make_float2(t4.x, t4.y);
        pv[2 * q + 1] = make_float2(t4.z, t4.w);
    }
    float s2e = 0.f, s2o = 0.f;
    int curbin = -1;
    float a0 = 0.f, a1 = 0.f, a2 = 0.f;
    #pragma unroll
    for (int j = 0; j < 8; ++j) {
        int ky = ky0 + j;
        int dy = ky - 512;
        int d2 = dy * dy + dx2;
        int bin = (int)sqrtf((float)d2);
        if ((bin + 1) * (bin + 1) <= d2) ++bin;
        else if (bin * bin > d2) --bin;
        bool ek = ((ky & 511) == 0);
        float w = ek ? (xs ? 1.f : 2.f) : 2.f;
        bool exc = (ek && xhi) || (ky == 0 && xcol == 0);
        float wc = exc ? 0.f : w;
        float v0 = w * pv[j].x, v1 = w * pv[j].y;
        s2e += v0 * pv[j].x;
        s2o += v1 * pv[j].y;
        if (bin == curbin) { a0 += v0; a1 += v1; a2 += wc; }
        else {
            if (curbin >= 0) {
                atomicAdd(&hs0[curbin], a0); atomicAdd(&hs1[curbin], a1);
                if (docnt && a2 != 0.f) atomicAdd(&hc[curbin], a2);
            }
            curbin = bin; a0 = v0; a1 = v1; a2 = wc;
        }
    }
    if (curbin >= 0) {
        atomicAdd(&hs0[curbin], a0); atomicAdd(&hs1[curbin], a1);
        if (docnt && a2 != 0.f) atomicAdd(&hc[curbin], a2);
    }
    // ky = 512 row (seg1 only): threads 0..7, one pixel each
    if (seg && tid < 8) {
        int x2 = (ch << 3) + tid;
        float2 pvv = base[((size_t)tid << 10) + 512];
        float w = ((x2 & 511) == 0) ? 1.f : 2.f;
        float v0 = w * pvv.x, v1 = w * pvv.y;
        s2e += v0 * pvv.x;
        s2o += v1 * pvv.y;
        int dx = x2 - 512;
        int bin = (dx < 0) ? -dx : dx;    // exact: dy = 0
        atomicAdd(&hs0[bin], v0);
        atomicAdd(&hs1[bin], v1);
        if (docnt && x2 <= 512) atomicAdd(&hc[bin], w);
    }
    #pragma unroll
    for (int off = 32; off > 0; off >>= 1) {
        s2e += __shfl_down(s2e, off);
        s2o += __shfl_down(s2o, off);
    }
    if ((tid & 63) == 0) { wred[tid >> 6] = s2e; wred[4 + (tid >> 6)] = s2o; }
    __syncthreads();
    if (tid == 0) s2buf[2 * blk]     = wred[0] + wred[1] + wred[2] + wred[3];
    if (tid == 1) s2buf[2 * blk + 1] = wred[4] + wred[5] + wred[6] + wred[7];
    // coalesced partial store: slice (sc = seg*128+ch) of this pair's region
    float* pbase = (float*)(spec + ((size_t)p << 20)) + PAIR_PARTIAL_OFF;
    int sc = (seg << 7) | ch;
    float* pe = pbase + (size_t)sc * NBINS;
    float* po = pe + PARTIAL_BATCH_STRIDE;
    float* pc = cntp + (size_t)sc * NBINS;
    for (int i = tid; i < NBINS; i += 256) {
        pe[i] = hs0[i];
        po[i] = hs1[i];
        if (docnt) pc[i] = hc[i];
    }
}

// Pass 4: one 64-lane wave per (b,bin) row: reduce 256 value slices and
// 256 count slices, store S^2/cnt to rowval[row]. No atomics.
__global__ __launch_bounds__(256) void reduce_loss(const float2* __restrict__ spec,
                                                   const float* __restrict__ cntp,
                                                   float* __restrict__ rowval) {
    int row = (blockIdx.x << 2) + (threadIdx.x >> 6);   // b*NBINS + bin
    int lane = threadIdx.x & 63;
    int b = row / NBINS, bin = row - b * NBINS;
    int p = b >> 1, eo = b & 1;
    const float* rp = (const float*)(spec + ((size_t)p << 20)) + PAIR_PARTIAL_OFF
                      + (size_t)eo * PARTIAL_BATCH_STRIDE + bin;
    const float* cp = cntp + bin;
    float s = 0.f, cv = 0.f;
    #pragma unroll
    for (int q = 0; q < 4; ++q) {
        size_t sc = (size_t)(lane + (q << 6));
        s  += rp[sc * NBINS];
        cv += cp[sc * NBINS];
    }
    #pragma unroll
    for (int off = 32; off > 0; off >>= 1) {
        s  += __shfl_down(s, off);
        cv += __shfl_down(cv, off);
    }
    if (lane == 0)
        rowval[row] = (cv > 0.f) ? s * s / cv : 0.f;
}

// Final: out = WA/B * (sum s2buf - sum rowval)
__global__ __launch_bounds__(256) void final_out(const float* __restrict__ s2buf,
                                                 const float* __restrict__ rowval,
                                                 float* __restrict__ out) {
    __shared__ float red[256];
    int tid = threadIdx.x;
    float acc = 0.f;
    for (int i = tid; i < NB * NBINS; i += 256) acc -= rowval[i];
    for (int i = tid; i < 2 * NPAIR * 256; i += 256) acc += s2buf[i];
    red[tid] = acc;
    __syncthreads();
    for (int s = 128; s > 0; s >>= 1) {
        if (tid < s) red[tid] += red[tid + s];
        __syncthreads();
    }
    if (tid == 0) out[0] = red[0] * (0.002f / 16.0f);
}

extern "C" void kernel_launch(void* const* d_in, const int* in_sizes, int n_in,
                              void* d_out, int out_size, void* d_ws, size_t ws_size,
                              hipStream_t stream) {
    const float* in = (const float*)d_in[0];
    float* out = (float*)d_out;
    char* ws = (char*)d_ws;

    float2* spec  = (float2*)ws;                                  // 64 MiB
    float* s2buf  = (float*)(ws + ((size_t)NPAIR << 20) * sizeof(float2));
    float* rowval = s2buf + 2 * NPAIR * 256;                      // 4096 floats
    float* cntp   = rowval + NB * NBINS;                          // 11600 floats
                                                                  // cntp: 185600 floats

    fft_rows<<<NPAIR * 128, 256, 0, stream>>>(in, spec);
    fft_cols_pow<<<NPAIR * 128, 256, 0, stream>>>(spec);
    radial_hist<<<NPAIR * 256, 256, 0, stream>>>(spec, s2buf, cntp);
    reduce_loss<<<NB * NBINS / 4, 256, 0, stream>>>(spec, cntp, rowval);
    final_out<<<1, 256, 0, stream>>>(s2buf, rowval, out);
}